// Round 4
// baseline (5598.083 us; speedup 1.0000x reference)
//
#include <hip/hip_runtime.h>
#include <math.h>

#define HIDDEN 768
#define NHEADS 12
#define HDIM   64
#define NTOK   1024   // 32*32
#define BATCH  8
#define CIN    256

// Gaussian weight, inference buffers mu=0 sigma=1: mean over k in {0.5,1,2} of
// exp(-x^2 / (2 (k sigma)^2 + eps))
__device__ __forceinline__ float gaussw(float x){
    float x2 = x * x;
    return (expf(-x2 / 0.50001f) + expf(-x2 / 2.00001f) + expf(-x2 / 8.00001f)) * (1.0f / 3.0f);
}

// ------------------------------------------------- tokens = proj(feat_b)+b+PE
// feat [B, C, N], per-batch: tok[n, d] = sum_c feat[b,c,n] W[c,d] + pb[d] + pe(n,d)
__global__ __launch_bounds__(256) void tokens_gemm(
    const float* __restrict__ feat, int b, const float* __restrict__ Wp,
    const float* __restrict__ pb, float* __restrict__ tok)
{
    __shared__ float As[64][65];   // As[kk][i]
    __shared__ float Bs[64][65];   // Bs[kk][j]
    const int t  = threadIdx.x;
    const int n0 = blockIdx.x * 64;          // token row within batch
    const int d0 = blockIdx.y * 64;
    const int ty = t / 16, tx = t % 16;
    float acc[4][4] = {};

    for (int k0 = 0; k0 < CIN; k0 += 64) {
        #pragma unroll
        for (int it = 0; it < 16; it++) {
            int e = t + 256 * it;
            int i = e % 64, kk = e / 64;
            As[kk][i] = feat[((size_t)b * CIN + (k0 + kk)) * NTOK + n0 + i];
        }
        #pragma unroll
        for (int it = 0; it < 16; it++) {
            int e = t + 256 * it;
            int j = e % 64, kk = e / 64;
            Bs[kk][j] = Wp[(size_t)(k0 + kk) * HIDDEN + d0 + j];
        }
        __syncthreads();
        for (int kk = 0; kk < 64; kk++) {
            float a[4], w[4];
            #pragma unroll
            for (int ii = 0; ii < 4; ii++) a[ii] = As[kk][ty * 4 + ii];
            #pragma unroll
            for (int jj = 0; jj < 4; jj++) w[jj] = Bs[kk][tx * 4 + jj];
            #pragma unroll
            for (int ii = 0; ii < 4; ii++)
                #pragma unroll
                for (int jj = 0; jj < 4; jj++)
                    acc[ii][jj] += a[ii] * w[jj];
        }
        __syncthreads();
    }

    const float kfac = -9.210340371976184f / 768.0f;  // -ln(10000)/HIDDEN
    #pragma unroll
    for (int ii = 0; ii < 4; ii++) {
        int n = n0 + ty * 4 + ii;
        #pragma unroll
        for (int jj = 0; jj < 4; jj++) {
            int d  = d0 + tx * 4 + jj;
            int j2 = d >> 1;
            float ang = (float)n * expf((float)(2 * j2) * kfac);
            float pe  = (d & 1) ? cosf(ang) : sinf(ang);
            tok[(size_t)n * HIDDEN + d] = acc[ii][jj] + pb[d] + pe;
        }
    }
}

// ---------------------------------------------------- GEMM + bias, M=1024
// A [1024,768] f32, W [768,768] f32, bias[768], out [1024,768] f32
__global__ __launch_bounds__(256) void gemm_bias(
    const float* __restrict__ A, const float* __restrict__ W,
    const float* __restrict__ bias, float* __restrict__ out)
{
    __shared__ float As[64][65];
    __shared__ float Bs[64][65];
    const int t  = threadIdx.x;
    const int m0 = blockIdx.x * 64;
    const int n0 = blockIdx.y * 64;
    const int ty = t / 16, tx = t % 16;
    float acc[4][4] = {};

    for (int k0 = 0; k0 < HIDDEN; k0 += 64) {
        #pragma unroll
        for (int it = 0; it < 16; it++) {
            int e = t + 256 * it;
            int kk = e % 64, i = e / 64;
            As[kk][i] = A[(size_t)(m0 + i) * HIDDEN + k0 + kk];
        }
        #pragma unroll
        for (int it = 0; it < 16; it++) {
            int e = t + 256 * it;
            int j = e % 64, kk = e / 64;
            Bs[kk][j] = W[(size_t)(k0 + kk) * HIDDEN + n0 + j];
        }
        __syncthreads();
        for (int kk = 0; kk < 64; kk++) {
            float a[4], w[4];
            #pragma unroll
            for (int ii = 0; ii < 4; ii++) a[ii] = As[kk][ty * 4 + ii];
            #pragma unroll
            for (int jj = 0; jj < 4; jj++) w[jj] = Bs[kk][tx * 4 + jj];
            #pragma unroll
            for (int ii = 0; ii < 4; ii++)
                #pragma unroll
                for (int jj = 0; jj < 4; jj++)
                    acc[ii][jj] += a[ii] * w[jj];
        }
        __syncthreads();
    }
    #pragma unroll
    for (int ii = 0; ii < 4; ii++) {
        size_t row = (size_t)(m0 + ty * 4 + ii);
        #pragma unroll
        for (int jj = 0; jj < 4; jj++) {
            int d = n0 + tx * 4 + jj;
            out[row * HIDDEN + d] = acc[ii][jj] + bias[d];
        }
    }
}

// ------------------------------------------------------------- attention (one batch)
// q,k,v [1024, 768] f32 (head h = cols h*64..), I full [B*N] f32, out ao [1024,768]
__global__ __launch_bounds__(256) void attn_kernel(
    const float* __restrict__ q, const float* __restrict__ k, const float* __restrict__ v,
    const float* __restrict__ I, int b, const float* __restrict__ lam_p, float* __restrict__ out)
{
    __shared__ float Qs[64][65];
    __shared__ float Ks[64][65];
    __shared__ float Vs[64][65];
    __shared__ float Ss[64][65];
    __shared__ float alphaS[64];
    __shared__ float lsumS[64];

    const int t   = threadIdx.x;
    const int h   = blockIdx.x / 16;
    const int qt  = blockIdx.x % 16;
    const float lam = lam_p[0];

    #pragma unroll
    for (int it = 0; it < 16; it++) {
        int e = t + 256 * it;
        int r = e / 64, d = e % 64;
        Qs[r][d] = q[(size_t)(qt * 64 + r) * HIDDEN + h * HDIM + d];
    }
    const int rg = t / 16, cg = t % 16;
    float acc_o[4][4] = {};
    float m_run = -1e30f, l_run = 0.0f;   // row t (t<64)
    float gi[4];
    #pragma unroll
    for (int ri = 0; ri < 4; ri++)
        gi[ri] = gaussw(I[b * NTOK + qt * 64 + 4 * rg + ri]);
    __syncthreads();

    for (int jt = 0; jt < 16; jt++) {
        #pragma unroll
        for (int it = 0; it < 16; it++) {
            int e = t + 256 * it;
            int r = e / 64, d = e % 64;
            size_t off = (size_t)(jt * 64 + r) * HIDDEN + h * HDIM + d;
            Ks[r][d] = k[off];
            Vs[r][d] = v[off];
        }
        __syncthreads();

        float gj[4];
        #pragma unroll
        for (int ji = 0; ji < 4; ji++)
            gj[ji] = gaussw(I[b * NTOK + jt * 64 + 4 * cg + ji]);
        float s[4][4] = {};
        for (int dd = 0; dd < 64; dd++) {
            float qa[4], kb[4];
            #pragma unroll
            for (int ri = 0; ri < 4; ri++) qa[ri] = Qs[4 * rg + ri][dd];
            #pragma unroll
            for (int ji = 0; ji < 4; ji++) kb[ji] = Ks[4 * cg + ji][dd];
            #pragma unroll
            for (int ri = 0; ri < 4; ri++)
                #pragma unroll
                for (int ji = 0; ji < 4; ji++)
                    s[ri][ji] += qa[ri] * kb[ji];
        }
        #pragma unroll
        for (int ri = 0; ri < 4; ri++)
            #pragma unroll
            for (int ji = 0; ji < 4; ji++)
                Ss[4 * rg + ri][4 * cg + ji] = s[ri][ji] * 0.125f + lam * gi[ri] * gj[ji];
        __syncthreads();

        if (t < 64) {
            float mx = m_run;
            for (int j = 0; j < 64; j++) mx = fmaxf(mx, Ss[t][j]);
            float alpha = expf(m_run - mx);
            float lsum  = l_run * alpha;
            for (int j = 0; j < 64; j++) {
                float p = expf(Ss[t][j] - mx);
                Ss[t][j] = p;
                lsum += p;
            }
            m_run = mx; l_run = lsum;
            alphaS[t] = alpha; lsumS[t] = lsum;
        }
        __syncthreads();

        #pragma unroll
        for (int ri = 0; ri < 4; ri++) {
            float alpha = alphaS[4 * rg + ri];
            #pragma unroll
            for (int di = 0; di < 4; di++) acc_o[ri][di] *= alpha;
        }
        for (int j = 0; j < 64; j++) {
            float p[4], vv[4];
            #pragma unroll
            for (int ri = 0; ri < 4; ri++) p[ri] = Ss[4 * rg + ri][j];
            #pragma unroll
            for (int di = 0; di < 4; di++) vv[di] = Vs[j][4 * cg + di];
            #pragma unroll
            for (int ri = 0; ri < 4; ri++)
                #pragma unroll
                for (int di = 0; di < 4; di++)
                    acc_o[ri][di] += p[ri] * vv[di];
        }
        __syncthreads();
    }

    #pragma unroll
    for (int ri = 0; ri < 4; ri++) {
        int r = 4 * rg + ri;
        float inv_l = 1.0f / lsumS[r];
        #pragma unroll
        for (int di = 0; di < 4; di++)
            out[(size_t)(qt * 64 + r) * HIDDEN + h * HDIM + 4 * cg + di] = acc_o[ri][di] * inv_l;
    }
}

// ---------------------------------------------------------------- launch
extern "C" void kernel_launch(void* const* d_in, const int* in_sizes, int n_in,
                              void* d_out, int out_size, void* d_ws, size_t ws_size,
                              hipStream_t stream)
{
    const float* feat   = (const float*)d_in[0];
    const float* I      = (const float*)d_in[1];
    const float* proj_w = (const float*)d_in[2];
    const float* proj_b = (const float*)d_in[3];
    const float* wq     = (const float*)d_in[4];
    const float* bq     = (const float*)d_in[5];
    const float* wk     = (const float*)d_in[6];
    const float* bk     = (const float*)d_in[7];
    const float* wv     = (const float*)d_in[8];
    const float* bv     = (const float*)d_in[9];
    const float* wo     = (const float*)d_in[10];
    const float* bo     = (const float*)d_in[11];
    const float* lam    = (const float*)d_in[12];
    float* out = (float*)d_out;

    const size_t BTOK = (size_t)NTOK * HIDDEN;   // 786432 elems = 3.15 MB fp32

    // ws usage: 4 x 3.15 MB = 12.6 MB total
    float* tok = (float*)d_ws;
    float* qm  = tok + BTOK;
    float* km  = qm + BTOK;
    float* ao  = km + BTOK;

    for (int b = 0; b < BATCH; b++) {
        float* vm    = out + (size_t)b * BTOK;   // v in d_out batch region, dead before final GEMM
        float* out_b = out + (size_t)b * BTOK;

        tokens_gemm<<<dim3(NTOK / 64, HIDDEN / 64), 256, 0, stream>>>(feat, b, proj_w, proj_b, tok);
        gemm_bias<<<dim3(NTOK / 64, HIDDEN / 64), 256, 0, stream>>>(tok, wq, bq, qm);
        gemm_bias<<<dim3(NTOK / 64, HIDDEN / 64), 256, 0, stream>>>(tok, wk, bk, km);
        gemm_bias<<<dim3(NTOK / 64, HIDDEN / 64), 256, 0, stream>>>(tok, wv, bv, vm);
        attn_kernel<<<NHEADS * (NTOK / 64), 256, 0, stream>>>(qm, km, vm, I, b, lam, ao);
        gemm_bias<<<dim3(NTOK / 64, HIDDEN / 64), 256, 0, stream>>>(ao, wo, bo, out_b);
    }
}

// Round 5
// 922.866 us; speedup vs baseline: 6.0660x; 6.0660x over previous
//
#include <hip/hip_runtime.h>
#include <hip/hip_bf16.h>
#include <math.h>

#define HIDDEN 768
#define NHEADS 12
#define HDIM   64
#define NTOK   1024   // 32*32
#define BATCH  8
#define CIN    256
#define M_ALL  (BATCH * NTOK)   // 8192

typedef __hip_bfloat16 bf16;
typedef short frag8 __attribute__((ext_vector_type(8)));   // 8 bf16 = 4 VGPRs
typedef float f32x4 __attribute__((ext_vector_type(4)));

__device__ __forceinline__ short f2bs(float x){
    union { bf16 h; short s; } u; u.h = __float2bfloat16(x); return u.s;
}
__device__ __forceinline__ float bs2f(short s){
    union { short s; bf16 h; } u; u.s = s; return __bfloat162float(u.h);
}

// Gaussian weight (inference buffers mu=0 sigma=1)
__device__ __forceinline__ float gaussw(float x){
    float x2 = x * x;
    return (expf(-x2 / 0.50001f) + expf(-x2 / 2.00001f) + expf(-x2 / 8.00001f)) * (1.0f / 3.0f);
}

// ------------------------------------------------------------ transpose+cvt
// in: f32 [K][N] (+ z*in_z), out: bf16 [N][K] (+ z*out_z)
__global__ __launch_bounds__(256) void transpose_cvt(
    const float* __restrict__ in, short* __restrict__ out,
    int K, int N, long in_z, long out_z)
{
    __shared__ short t[64][65];
    const float* W  = in  + (size_t)blockIdx.z * in_z;
    short*       WT = out + (size_t)blockIdx.z * out_z;
    const int k0 = blockIdx.x * 64, n0 = blockIdx.y * 64;
    const int tid = threadIdx.x;
    #pragma unroll
    for (int it = 0; it < 16; it++) {
        int e = tid + 256 * it;
        int kk = e / 64, nn = e % 64;
        t[kk][nn] = f2bs(W[(size_t)(k0 + kk) * N + n0 + nn]);
    }
    __syncthreads();
    #pragma unroll
    for (int it = 0; it < 16; it++) {
        int e = tid + 256 * it;
        int nn = e / 64, kk = e % 64;          // kk fastest -> coalesced store
        WT[(size_t)(n0 + nn) * K + k0 + kk] = t[kk][nn];
    }
}

// ------------------------------------------------------------ MFMA GEMM
// A bf16 [M_ALL][K] row-major; WT bf16 [768][K] (= W^T); bias f32 [768].
// MODE 0: out bf16 = acc+bias   (QKV)
// MODE 1: out bf16 = acc+bias+PE(n,d)   (tokens)
// MODE 2: out f32  = acc+bias   (final projection)
// grid: (M_ALL/128, 768/128, Z); z selects WT plane / bias / out.
template<int MODE>
__global__ __launch_bounds__(256) void gemm_mfma(
    const short* __restrict__ A, const short* __restrict__ WT0, long wt_z,
    const float* __restrict__ b0, const float* __restrict__ b1, const float* __restrict__ b2,
    void* o0, void* o1, void* o2, int K)
{
    __shared__ short Al[128 * 40];   // [row][k] pad 32->40 shorts (80B stride)
    __shared__ short Bl[128 * 40];   // [n][k]
    const int z = blockIdx.z;
    const short* WT  = WT0 + (size_t)z * wt_z;
    const float* bias = (z == 0) ? b0 : (z == 1) ? b1 : b2;
    void* outv        = (z == 0) ? o0 : (z == 1) ? o1 : o2;

    const int tid  = threadIdx.x;
    const int m0   = blockIdx.x * 128;
    const int n0   = blockIdx.y * 128;
    const int lane = tid & 63, wid = tid >> 6;
    const int wm   = (wid >> 1) * 64, wn = (wid & 1) * 64;
    const int l16  = lane & 15, quad = lane >> 4;

    const f32x4 z4 = {0.f, 0.f, 0.f, 0.f};
    f32x4 acc[4][4];
    #pragma unroll
    for (int i = 0; i < 4; i++)
        #pragma unroll
        for (int j = 0; j < 4; j++) acc[i][j] = z4;

    for (int k0 = 0; k0 < K; k0 += 32) {
        #pragma unroll
        for (int it = 0; it < 2; it++) {
            int e = tid + 256 * it;          // 0..511
            int r = e >> 2;                  // 0..127
            int s = e & 3;                   // 8-short segment
            frag8 va = *(const frag8*)&A [(size_t)(m0 + r) * K + k0 + s * 8];
            *(frag8*)&Al[r * 40 + s * 8] = va;
            frag8 vb = *(const frag8*)&WT[(size_t)(n0 + r) * K + k0 + s * 8];
            *(frag8*)&Bl[r * 40 + s * 8] = vb;
        }
        __syncthreads();
        frag8 af[4], bfr[4];
        #pragma unroll
        for (int i = 0; i < 4; i++) af[i]  = *(const frag8*)&Al[(wm + i * 16 + l16) * 40 + quad * 8];
        #pragma unroll
        for (int j = 0; j < 4; j++) bfr[j] = *(const frag8*)&Bl[(wn + j * 16 + l16) * 40 + quad * 8];
        #pragma unroll
        for (int i = 0; i < 4; i++)
            #pragma unroll
            for (int j = 0; j < 4; j++)
                acc[i][j] = __builtin_amdgcn_mfma_f32_16x16x32_bf16(af[i], bfr[j], acc[i][j], 0, 0, 0);
        __syncthreads();
    }

    const float kfac = -9.210340371976184f / 768.0f;  // -ln(10000)/HIDDEN
    #pragma unroll
    for (int i = 0; i < 4; i++) {
        #pragma unroll
        for (int r = 0; r < 4; r++) {
            int m = m0 + wm + i * 16 + quad * 4 + r;   // C/D: row = quad*4+reg
            #pragma unroll
            for (int j = 0; j < 4; j++) {
                int col = n0 + wn + j * 16 + l16;      // C/D: col = lane&15
                float val = acc[i][j][r] + bias[col];
                if (MODE == 1) {
                    int n_tok = m & (NTOK - 1);
                    float ang = (float)n_tok * expf((float)(2 * (col >> 1)) * kfac);
                    val += (col & 1) ? cosf(ang) : sinf(ang);
                }
                if (MODE == 2) ((float*)outv)[(size_t)m * HIDDEN + col] = val;
                else           ((short*)outv)[(size_t)m * HIDDEN + col] = f2bs(val);
            }
        }
    }
}

// ------------------------------------------------------------- attention
// q,k,v bf16 [8192][768]; I f32 [8192]; ao bf16 [8192][768]. grid = B*NH*16.
__global__ __launch_bounds__(256) void attn_kernel(
    const short* __restrict__ q, const short* __restrict__ k, const short* __restrict__ v,
    const float* __restrict__ I, const float* __restrict__ lam_p, short* __restrict__ out)
{
    __shared__ float Qs[64][65];
    __shared__ float Ks[64][65];
    __shared__ float Vs[64][65];
    __shared__ float Ss[64][65];
    __shared__ float alphaS[64];
    __shared__ float lsumS[64];

    const int t   = threadIdx.x;
    const int bid = blockIdx.x;
    const int b   = bid / (NHEADS * 16);
    const int h   = (bid / 16) % NHEADS;
    const int qt  = bid % 16;
    const float lam = lam_p[0];

    #pragma unroll
    for (int it = 0; it < 16; it++) {
        int e = t + 256 * it;
        int r = e / 64, d = e % 64;
        Qs[r][d] = bs2f(q[(size_t)(b * NTOK + qt * 64 + r) * HIDDEN + h * HDIM + d]);
    }
    const int rg = t / 16, cg = t % 16;
    float acc_o[4][4] = {};
    float m_run = -1e30f, l_run = 0.0f;   // row t (t<64)
    float gi[4];
    #pragma unroll
    for (int ri = 0; ri < 4; ri++)
        gi[ri] = gaussw(I[b * NTOK + qt * 64 + 4 * rg + ri]);
    __syncthreads();

    for (int jt = 0; jt < 16; jt++) {
        #pragma unroll
        for (int it = 0; it < 16; it++) {
            int e = t + 256 * it;
            int r = e / 64, d = e % 64;
            size_t off = (size_t)(b * NTOK + jt * 64 + r) * HIDDEN + h * HDIM + d;
            Ks[r][d] = bs2f(k[off]);
            Vs[r][d] = bs2f(v[off]);
        }
        __syncthreads();

        float gj[4];
        #pragma unroll
        for (int ji = 0; ji < 4; ji++)
            gj[ji] = gaussw(I[b * NTOK + jt * 64 + 4 * cg + ji]);
        float s[4][4] = {};
        for (int dd = 0; dd < 64; dd++) {
            float qa[4], kb[4];
            #pragma unroll
            for (int ri = 0; ri < 4; ri++) qa[ri] = Qs[4 * rg + ri][dd];
            #pragma unroll
            for (int ji = 0; ji < 4; ji++) kb[ji] = Ks[4 * cg + ji][dd];
            #pragma unroll
            for (int ri = 0; ri < 4; ri++)
                #pragma unroll
                for (int ji = 0; ji < 4; ji++)
                    s[ri][ji] += qa[ri] * kb[ji];
        }
        #pragma unroll
        for (int ri = 0; ri < 4; ri++)
            #pragma unroll
            for (int ji = 0; ji < 4; ji++)
                Ss[4 * rg + ri][4 * cg + ji] = s[ri][ji] * 0.125f + lam * gi[ri] * gj[ji];
        __syncthreads();

        if (t < 64) {
            float mx = m_run;
            for (int j = 0; j < 64; j++) mx = fmaxf(mx, Ss[t][j]);
            float alpha = expf(m_run - mx);
            float lsum  = l_run * alpha;
            for (int j = 0; j < 64; j++) {
                float p = expf(Ss[t][j] - mx);
                Ss[t][j] = p;
                lsum += p;
            }
            m_run = mx; l_run = lsum;
            alphaS[t] = alpha; lsumS[t] = lsum;
        }
        __syncthreads();

        #pragma unroll
        for (int ri = 0; ri < 4; ri++) {
            float alpha = alphaS[4 * rg + ri];
            #pragma unroll
            for (int di = 0; di < 4; di++) acc_o[ri][di] *= alpha;
        }
        for (int j = 0; j < 64; j++) {
            float p[4], vv[4];
            #pragma unroll
            for (int ri = 0; ri < 4; ri++) p[ri] = Ss[4 * rg + ri][j];
            #pragma unroll
            for (int di = 0; di < 4; di++) vv[di] = Vs[j][4 * cg + di];
            #pragma unroll
            for (int ri = 0; ri < 4; ri++)
                #pragma unroll
                for (int di = 0; di < 4; di++)
                    acc_o[ri][di] += p[ri] * vv[di];
        }
        __syncthreads();
    }

    #pragma unroll
    for (int ri = 0; ri < 4; ri++) {
        int r = 4 * rg + ri;
        float inv_l = 1.0f / lsumS[r];
        #pragma unroll
        for (int di = 0; di < 4; di++)
            out[(size_t)(b * NTOK + qt * 64 + r) * HIDDEN + h * HDIM + 4 * cg + di]
                = f2bs(acc_o[ri][di] * inv_l);
    }
}

// ---------------------------------------------------------------- launch
extern "C" void kernel_launch(void* const* d_in, const int* in_sizes, int n_in,
                              void* d_out, int out_size, void* d_ws, size_t ws_size,
                              hipStream_t stream)
{
    const float* feat   = (const float*)d_in[0];
    const float* I      = (const float*)d_in[1];
    const float* proj_w = (const float*)d_in[2];
    const float* proj_b = (const float*)d_in[3];
    const float* wq     = (const float*)d_in[4];
    const float* bq     = (const float*)d_in[5];
    const float* wk     = (const float*)d_in[6];
    const float* bk     = (const float*)d_in[7];
    const float* wv     = (const float*)d_in[8];
    const float* bv     = (const float*)d_in[9];
    const float* wo     = (const float*)d_in[10];
    const float* bo     = (const float*)d_in[11];
    const float* lam    = (const float*)d_in[12];
    float* out = (float*)d_out;

    // ws layout (bf16/short elements), ~30.3 MB total:
    //  wtqkv [3][768][768] | wto [768][768] | wtp [768][256] | tokens/ao [8192][768] | featT->q [8192][768]
    short* wtqkv = (short*)d_ws;
    short* wto   = wtqkv + (size_t)3 * HIDDEN * HIDDEN;
    short* wtp   = wto   + (size_t)HIDDEN * HIDDEN;
    short* tokens= wtp   + (size_t)HIDDEN * CIN;
    short* qbuf  = tokens+ (size_t)M_ALL * HIDDEN;       // featT first, q later (featT dead)
    short* featT = qbuf;                                  // [B][1024][256] = 4.19MB < 12.58MB
    short* ao    = tokens;                                // alias: tokens dead after QKV
    short* kbuf  = (short*)d_out;                         // k,v in d_out (dead before final write)
    short* vbuf  = kbuf + (size_t)M_ALL * HIDDEN;

    // 1. weight transposes (f32 [K][N] -> bf16 [N][K])
    transpose_cvt<<<dim3(12, 12, 1), 256, 0, stream>>>(wq,     wtqkv,                 768, 768, 0, 0);
    transpose_cvt<<<dim3(12, 12, 1), 256, 0, stream>>>(wk,     wtqkv + 768 * 768,     768, 768, 0, 0);
    transpose_cvt<<<dim3(12, 12, 1), 256, 0, stream>>>(wv,     wtqkv + 2 * 768 * 768, 768, 768, 0, 0);
    transpose_cvt<<<dim3(12, 12, 1), 256, 0, stream>>>(wo,     wto,                   768, 768, 0, 0);
    transpose_cvt<<<dim3(4,  12, 1), 256, 0, stream>>>(proj_w, wtp,                   256, 768, 0, 0);
    // 2. feat [B][C][N] -> featT [B][N][C] bf16
    transpose_cvt<<<dim3(4, 16, 8), 256, 0, stream>>>(feat, featT, 256, 1024,
                                                      (long)CIN * NTOK, (long)NTOK * CIN);
    // 3. tokens = featT @ proj_w + b + PE   (MFMA, K=256)
    gemm_mfma<1><<<dim3(64, 6, 1), 256, 0, stream>>>(featT, wtp, 0,
                                                     proj_b, proj_b, proj_b,
                                                     tokens, tokens, tokens, CIN);
    // 4. fused QKV (grid.z selects weight/bias/out)
    gemm_mfma<0><<<dim3(64, 6, 3), 256, 0, stream>>>(tokens, wtqkv, (long)HIDDEN * HIDDEN,
                                                     bq, bk, bv,
                                                     qbuf, kbuf, vbuf, HIDDEN);
    // 5. attention (batch-wide)
    attn_kernel<<<BATCH * NHEADS * 16, 256, 0, stream>>>(qbuf, kbuf, vbuf, I, lam, ao);
    // 6. final projection (f32 out)
    gemm_mfma<2><<<dim3(64, 6, 1), 256, 0, stream>>>(ao, wto, 0,
                                                     bo, bo, bo,
                                                     out, out, out, HIDDEN);
}

// Round 6
// 352.838 us; speedup vs baseline: 15.8659x; 2.6155x over previous
//
#include <hip/hip_runtime.h>
#include <hip/hip_bf16.h>
#include <math.h>

#define HIDDEN 768
#define NHEADS 12
#define HDIM   64
#define NTOK   1024   // 32*32
#define BATCH  8
#define CIN    256
#define M_ALL  (BATCH * NTOK)   // 8192
#define LSTR   72               // attn LDS row stride in shorts (144B: 16B-aligned, <=2-way banks)

typedef __hip_bfloat16 bf16;
typedef short frag8 __attribute__((ext_vector_type(8)));   // 8 bf16 = 4 VGPRs
typedef float f32x4 __attribute__((ext_vector_type(4)));

__device__ __forceinline__ short f2bs(float x){
    union { bf16 h; short s; } u; u.h = __float2bfloat16(x); return u.s;
}
__device__ __forceinline__ float bs2f(short s){
    union { short s; bf16 h; } u; u.s = s; return __bfloat162float(u.h);
}

// Gaussian weight (inference buffers mu=0 sigma=1)
__device__ __forceinline__ float gaussw(float x){
    float x2 = x * x;
    return (__expf(-x2 / 0.50001f) + __expf(-x2 / 2.00001f) + __expf(-x2 / 8.00001f)) * (1.0f / 3.0f);
}

// ------------------------------------------------------------ transpose+cvt
// in: f32 [K][N] (+ z*in_z), out: bf16 [N][K] (+ z*out_z)
__global__ __launch_bounds__(256) void transpose_cvt(
    const float* __restrict__ in, short* __restrict__ out,
    int K, int N, long in_z, long out_z)
{
    __shared__ short t[64][65];
    const float* W  = in  + (size_t)blockIdx.z * in_z;
    short*       WT = out + (size_t)blockIdx.z * out_z;
    const int k0 = blockIdx.x * 64, n0 = blockIdx.y * 64;
    const int tid = threadIdx.x;
    #pragma unroll
    for (int it = 0; it < 16; it++) {
        int e = tid + 256 * it;
        int kk = e / 64, nn = e % 64;
        t[kk][nn] = f2bs(W[(size_t)(k0 + kk) * N + n0 + nn]);
    }
    __syncthreads();
    #pragma unroll
    for (int it = 0; it < 16; it++) {
        int e = tid + 256 * it;
        int nn = e / 64, kk = e % 64;          // kk fastest -> coalesced store
        WT[(size_t)(n0 + nn) * K + k0 + kk] = t[kk][nn];
    }
}

// ------------------------------------------------------------ MFMA GEMM
// A bf16 [M_ALL][K] row-major; WT bf16 [768][K] (= W^T); bias f32 [768].
// MODE 0: out bf16 = acc+bias   (QKV)
// MODE 1: out bf16 = acc+bias+PE(n,d)   (tokens)
// MODE 2: out f32  = acc+bias   (final projection)
template<int MODE>
__global__ __launch_bounds__(256) void gemm_mfma(
    const short* __restrict__ A, const short* __restrict__ WT0, long wt_z,
    const float* __restrict__ b0, const float* __restrict__ b1, const float* __restrict__ b2,
    void* o0, void* o1, void* o2, int K)
{
    __shared__ short Al[128 * 40];   // [row][k] pad 32->40 shorts (80B stride)
    __shared__ short Bl[128 * 40];   // [n][k]
    const int z = blockIdx.z;
    const short* WT  = WT0 + (size_t)z * wt_z;
    const float* bias = (z == 0) ? b0 : (z == 1) ? b1 : b2;
    void* outv        = (z == 0) ? o0 : (z == 1) ? o1 : o2;

    const int tid  = threadIdx.x;
    const int m0   = blockIdx.x * 128;
    const int n0   = blockIdx.y * 128;
    const int lane = tid & 63, wid = tid >> 6;
    const int wm   = (wid >> 1) * 64, wn = (wid & 1) * 64;
    const int l16  = lane & 15, quad = lane >> 4;

    const f32x4 z4 = {0.f, 0.f, 0.f, 0.f};
    f32x4 acc[4][4];
    #pragma unroll
    for (int i = 0; i < 4; i++)
        #pragma unroll
        for (int j = 0; j < 4; j++) acc[i][j] = z4;

    for (int k0 = 0; k0 < K; k0 += 32) {
        #pragma unroll
        for (int it = 0; it < 2; it++) {
            int e = tid + 256 * it;          // 0..511
            int r = e >> 2;                  // 0..127
            int s = e & 3;                   // 8-short segment
            frag8 va = *(const frag8*)&A [(size_t)(m0 + r) * K + k0 + s * 8];
            *(frag8*)&Al[r * 40 + s * 8] = va;
            frag8 vb = *(const frag8*)&WT[(size_t)(n0 + r) * K + k0 + s * 8];
            *(frag8*)&Bl[r * 40 + s * 8] = vb;
        }
        __syncthreads();
        frag8 af[4], bfr[4];
        #pragma unroll
        for (int i = 0; i < 4; i++) af[i]  = *(const frag8*)&Al[(wm + i * 16 + l16) * 40 + quad * 8];
        #pragma unroll
        for (int j = 0; j < 4; j++) bfr[j] = *(const frag8*)&Bl[(wn + j * 16 + l16) * 40 + quad * 8];
        #pragma unroll
        for (int i = 0; i < 4; i++)
            #pragma unroll
            for (int j = 0; j < 4; j++)
                acc[i][j] = __builtin_amdgcn_mfma_f32_16x16x32_bf16(af[i], bfr[j], acc[i][j], 0, 0, 0);
        __syncthreads();
    }

    const float kfac = -9.210340371976184f / 768.0f;  // -ln(10000)/HIDDEN
    #pragma unroll
    for (int i = 0; i < 4; i++) {
        #pragma unroll
        for (int r = 0; r < 4; r++) {
            int m = m0 + wm + i * 16 + quad * 4 + r;   // C/D: row = quad*4+reg
            #pragma unroll
            for (int j = 0; j < 4; j++) {
                int col = n0 + wn + j * 16 + l16;      // C/D: col = lane&15
                float val = acc[i][j][r] + bias[col];
                if (MODE == 1) {
                    int n_tok = m & (NTOK - 1);
                    float ang = (float)n_tok * expf((float)(2 * (col >> 1)) * kfac);
                    val += (col & 1) ? cosf(ang) : sinf(ang);
                }
                if (MODE == 2) ((float*)outv)[(size_t)m * HIDDEN + col] = val;
                else           ((short*)outv)[(size_t)m * HIDDEN + col] = f2bs(val);
            }
        }
    }
}

// ------------------------------------------------------------- MFMA flash attention
// q,k,v bf16 [8192][768]; I f32 [8192]; out bf16 [8192][768]. grid = B*NH*16 (qtile=64).
__global__ __launch_bounds__(256) void attn_mfma(
    const short* __restrict__ q, const short* __restrict__ k, const short* __restrict__ v,
    const float* __restrict__ I, const float* __restrict__ lam_p, short* __restrict__ out)
{
    __shared__ short Qs[64 * LSTR];
    __shared__ short Ks[64 * LSTR];
    __shared__ short Vs[64 * LSTR];
    __shared__ short Vt[64 * LSTR];   // Vt[d][key]
    __shared__ short Ps[64 * LSTR];   // P in [row][key]
    __shared__ float gL[NTOK];

    const int tid = threadIdx.x;
    const int bid = blockIdx.x;
    const int b   = bid / (NHEADS * 16);
    const int h   = (bid / 16) % NHEADS;
    const int qt  = bid % 16;
    const float lam = lam_p[0];
    const int lane = tid & 63, wave = tid >> 6;
    const int l16  = lane & 15, quad = lane >> 4;

    // gaussian weights for this batch's tokens
    for (int i = tid; i < NTOK; i += 256) gL[i] = gaussw(I[b * NTOK + i]);

    // stage Q tile [64 rows x 64 d]
    #pragma unroll
    for (int it = 0; it < 2; it++) {
        int e = tid + 256 * it;
        int r = e >> 3, seg = e & 7;
        *(frag8*)&Qs[r * LSTR + seg * 8] =
            *(const frag8*)&q[(size_t)(b * NTOK + qt * 64 + r) * HIDDEN + h * HDIM + seg * 8];
    }
    __syncthreads();

    // hoisted Q A-frags (wave's 16 rows), and per-row gaussian
    frag8 aq0 = *(const frag8*)&Qs[(wave * 16 + l16) * LSTR + quad * 8];
    frag8 aq1 = *(const frag8*)&Qs[(wave * 16 + l16) * LSTR + 32 + quad * 8];
    float gi[4];
    #pragma unroll
    for (int r = 0; r < 4; r++) gi[r] = gL[qt * 64 + wave * 16 + quad * 4 + r];

    const f32x4 z4 = {0.f, 0.f, 0.f, 0.f};
    f32x4 o_acc[4];
    #pragma unroll
    for (int d = 0; d < 4; d++) o_acc[d] = z4;
    float m_run[4] = {-1e30f, -1e30f, -1e30f, -1e30f};
    float l_run[4] = {0.f, 0.f, 0.f, 0.f};

    for (int jt = 0; jt < 16; jt++) {
        __syncthreads();    // prev iteration's Ks/Vt reads complete
        // stage K,V tile (coalesced)
        #pragma unroll
        for (int it = 0; it < 2; it++) {
            int e = tid + 256 * it;
            int r = e >> 3, seg = e & 7;
            size_t goff = (size_t)(b * NTOK + jt * 64 + r) * HIDDEN + h * HDIM + seg * 8;
            *(frag8*)&Ks[r * LSTR + seg * 8] = *(const frag8*)&k[goff];
            *(frag8*)&Vs[r * LSTR + seg * 8] = *(const frag8*)&v[goff];
        }
        __syncthreads();

        // transpose V -> Vt[d][key]
        #pragma unroll
        for (int it = 0; it < 2; it++) {
            int r   = (tid & 31) + 32 * it;
            int seg = tid >> 5;
            frag8 vv = *(const frag8*)&Vs[r * LSTR + seg * 8];
            #pragma unroll
            for (int j = 0; j < 8; j++)
                Vt[(seg * 8 + j) * LSTR + r] = vv[j];
        }

        // S = Q.K^T  (wave rows x 64 keys)
        f32x4 s_acc[4];
        #pragma unroll
        for (int t4 = 0; t4 < 4; t4++) {
            frag8 bk0 = *(const frag8*)&Ks[(t4 * 16 + l16) * LSTR + quad * 8];
            frag8 bk1 = *(const frag8*)&Ks[(t4 * 16 + l16) * LSTR + 32 + quad * 8];
            f32x4 a = z4;
            a = __builtin_amdgcn_mfma_f32_16x16x32_bf16(aq0, bk0, a, 0, 0, 0);
            a = __builtin_amdgcn_mfma_f32_16x16x32_bf16(aq1, bk1, a, 0, 0, 0);
            s_acc[t4] = a;
        }

        // online softmax in C/D layout: row = quad*4+reg, col = t4*16+l16
        float gj[4];
        #pragma unroll
        for (int t4 = 0; t4 < 4; t4++) gj[t4] = gL[jt * 64 + t4 * 16 + l16];

        float p[4][4], mx[4];
        #pragma unroll
        for (int r = 0; r < 4; r++) mx[r] = -1e30f;
        #pragma unroll
        for (int t4 = 0; t4 < 4; t4++)
            #pragma unroll
            for (int r = 0; r < 4; r++) {
                float sv = s_acc[t4][r] * 0.125f + lam * gi[r] * gj[t4];
                p[t4][r] = sv;
                mx[r] = fmaxf(mx[r], sv);
            }
        #pragma unroll
        for (int off = 1; off < 16; off <<= 1)
            #pragma unroll
            for (int r = 0; r < 4; r++) mx[r] = fmaxf(mx[r], __shfl_xor(mx[r], off));

        float alpha[4], ls[4];
        #pragma unroll
        for (int r = 0; r < 4; r++) {
            float mn = fmaxf(m_run[r], mx[r]);
            alpha[r] = __expf(m_run[r] - mn);
            m_run[r] = mn;
            ls[r] = 0.f;
        }
        #pragma unroll
        for (int t4 = 0; t4 < 4; t4++)
            #pragma unroll
            for (int r = 0; r < 4; r++) {
                float e = __expf(p[t4][r] - m_run[r]);
                p[t4][r] = e;
                ls[r] += e;
            }
        #pragma unroll
        for (int off = 1; off < 16; off <<= 1)
            #pragma unroll
            for (int r = 0; r < 4; r++) ls[r] += __shfl_xor(ls[r], off);
        #pragma unroll
        for (int r = 0; r < 4; r++) l_run[r] = l_run[r] * alpha[r] + ls[r];

        // rescale O
        #pragma unroll
        for (int d = 0; d < 4; d++)
            #pragma unroll
            for (int r = 0; r < 4; r++) o_acc[d][r] *= alpha[r];

        // P (C/D layout) -> LDS rows (wave-private rows)
        #pragma unroll
        for (int t4 = 0; t4 < 4; t4++)
            #pragma unroll
            for (int r = 0; r < 4; r++)
                Ps[(wave * 16 + quad * 4 + r) * LSTR + t4 * 16 + l16] = f2bs(p[t4][r]);
        __syncthreads();    // Vt (cross-wave) + Ps visible

        // O += P.V
        frag8 ap0 = *(const frag8*)&Ps[(wave * 16 + l16) * LSTR + quad * 8];
        frag8 ap1 = *(const frag8*)&Ps[(wave * 16 + l16) * LSTR + 32 + quad * 8];
        #pragma unroll
        for (int d = 0; d < 4; d++) {
            frag8 bv0 = *(const frag8*)&Vt[(d * 16 + l16) * LSTR + quad * 8];
            frag8 bv1 = *(const frag8*)&Vt[(d * 16 + l16) * LSTR + 32 + quad * 8];
            o_acc[d] = __builtin_amdgcn_mfma_f32_16x16x32_bf16(ap0, bv0, o_acc[d], 0, 0, 0);
            o_acc[d] = __builtin_amdgcn_mfma_f32_16x16x32_bf16(ap1, bv1, o_acc[d], 0, 0, 0);
        }
    }

    // epilogue: divide by l, store
    #pragma unroll
    for (int r = 0; r < 4; r++) {
        float inv_l = 1.0f / l_run[r];
        int row = qt * 64 + wave * 16 + quad * 4 + r;
        #pragma unroll
        for (int d = 0; d < 4; d++)
            out[(size_t)(b * NTOK + row) * HIDDEN + h * HDIM + d * 16 + l16]
                = f2bs(o_acc[d][r] * inv_l);
    }
}

// ---------------------------------------------------------------- launch
extern "C" void kernel_launch(void* const* d_in, const int* in_sizes, int n_in,
                              void* d_out, int out_size, void* d_ws, size_t ws_size,
                              hipStream_t stream)
{
    const float* feat   = (const float*)d_in[0];
    const float* I      = (const float*)d_in[1];
    const float* proj_w = (const float*)d_in[2];
    const float* proj_b = (const float*)d_in[3];
    const float* wq     = (const float*)d_in[4];
    const float* bq     = (const float*)d_in[5];
    const float* wk     = (const float*)d_in[6];
    const float* bk     = (const float*)d_in[7];
    const float* wv     = (const float*)d_in[8];
    const float* bv     = (const float*)d_in[9];
    const float* wo     = (const float*)d_in[10];
    const float* bo     = (const float*)d_in[11];
    const float* lam    = (const float*)d_in[12];
    float* out = (float*)d_out;

    // ws layout (bf16/short elements), ~30.3 MB total
    short* wtqkv = (short*)d_ws;
    short* wto   = wtqkv + (size_t)3 * HIDDEN * HIDDEN;
    short* wtp   = wto   + (size_t)HIDDEN * HIDDEN;
    short* tokens= wtp   + (size_t)HIDDEN * CIN;
    short* qbuf  = tokens+ (size_t)M_ALL * HIDDEN;       // featT first, q later (featT dead)
    short* featT = qbuf;                                  // [B][1024][256] = 4.19MB < 12.58MB
    short* ao    = tokens;                                // alias: tokens dead after QKV
    short* kbuf  = (short*)d_out;                         // k,v in d_out (dead before final write)
    short* vbuf  = kbuf + (size_t)M_ALL * HIDDEN;

    // 1. weight transposes (f32 [K][N] -> bf16 [N][K])
    transpose_cvt<<<dim3(12, 12, 1), 256, 0, stream>>>(wq,     wtqkv,                 768, 768, 0, 0);
    transpose_cvt<<<dim3(12, 12, 1), 256, 0, stream>>>(wk,     wtqkv + 768 * 768,     768, 768, 0, 0);
    transpose_cvt<<<dim3(12, 12, 1), 256, 0, stream>>>(wv,     wtqkv + 2 * 768 * 768, 768, 768, 0, 0);
    transpose_cvt<<<dim3(12, 12, 1), 256, 0, stream>>>(wo,     wto,                   768, 768, 0, 0);
    transpose_cvt<<<dim3(4,  12, 1), 256, 0, stream>>>(proj_w, wtp,                   256, 768, 0, 0);
    // 2. feat [B][C][N] -> featT [B][N][C] bf16
    transpose_cvt<<<dim3(4, 16, 8), 256, 0, stream>>>(feat, featT, 256, 1024,
                                                      (long)CIN * NTOK, (long)NTOK * CIN);
    // 3. tokens = featT @ proj_w + b + PE
    gemm_mfma<1><<<dim3(64, 6, 1), 256, 0, stream>>>(featT, wtp, 0,
                                                     proj_b, proj_b, proj_b,
                                                     tokens, tokens, tokens, CIN);
    // 4. fused QKV
    gemm_mfma<0><<<dim3(64, 6, 3), 256, 0, stream>>>(tokens, wtqkv, (long)HIDDEN * HIDDEN,
                                                     bq, bk, bv,
                                                     qbuf, kbuf, vbuf, HIDDEN);
    // 5. attention (MFMA flash)
    attn_mfma<<<BATCH * NHEADS * 16, 256, 0, stream>>>(qbuf, kbuf, vbuf, I, lam, ao);
    // 6. final projection (f32 out)
    gemm_mfma<2><<<dim3(64, 6, 1), 256, 0, stream>>>(ao, wto, 0,
                                                     bo, bo, bo,
                                                     out, out, out, HIDDEN);
}

// Round 7
// 329.644 us; speedup vs baseline: 16.9822x; 1.0704x over previous
//
#include <hip/hip_runtime.h>
#include <hip/hip_bf16.h>
#include <math.h>

#define HIDDEN 768
#define NHEADS 12
#define HDIM   64
#define NTOK   1024   // 32*32
#define BATCH  8
#define CIN    256
#define M_ALL  (BATCH * NTOK)   // 8192
#define LSTR   72               // attn LDS row stride in shorts (144B: 16B-aligned, <=2-way banks)

typedef __hip_bfloat16 bf16;
typedef short frag8 __attribute__((ext_vector_type(8)));   // 8 bf16 = 4 VGPRs
typedef float f32x4 __attribute__((ext_vector_type(4)));

__device__ __forceinline__ short f2bs(float x){
    union { bf16 h; short s; } u; u.h = __float2bfloat16(x); return u.s;
}

// Gaussian weight (inference buffers mu=0 sigma=1)
__device__ __forceinline__ float gaussw(float x){
    float x2 = x * x;
    return (__expf(-x2 / 0.50001f) + __expf(-x2 / 2.00001f) + __expf(-x2 / 8.00001f)) * (1.0f / 3.0f);
}

// ------------------------------------------------------------ transpose+cvt (generic, f32 -> bf16)
// in: f32 [K][N] (+ z*in_z), out: bf16 [N][K] (+ z*out_z)
__global__ __launch_bounds__(256) void transpose_cvt(
    const float* __restrict__ in, short* __restrict__ out,
    int K, int N, long in_z, long out_z)
{
    __shared__ short t[64][65];
    const float* W  = in  + (size_t)blockIdx.z * in_z;
    short*       WT = out + (size_t)blockIdx.z * out_z;
    const int k0 = blockIdx.x * 64, n0 = blockIdx.y * 64;
    const int tid = threadIdx.x;
    #pragma unroll
    for (int it = 0; it < 16; it++) {
        int e = tid + 256 * it;
        int kk = e / 64, nn = e % 64;
        t[kk][nn] = f2bs(W[(size_t)(k0 + kk) * N + n0 + nn]);
    }
    __syncthreads();
    #pragma unroll
    for (int it = 0; it < 16; it++) {
        int e = tid + 256 * it;
        int nn = e / 64, kk = e % 64;          // kk fastest -> coalesced store
        WT[(size_t)(n0 + nn) * K + k0 + kk] = t[kk][nn];
    }
}

// ------------------------------------------------------------ fused 4x 768x768 weight transpose
__global__ __launch_bounds__(256) void transpose_w4(
    const float* __restrict__ w0, const float* __restrict__ w1,
    const float* __restrict__ w2, const float* __restrict__ w3,
    short* __restrict__ dstbase)
{
    __shared__ short t[64][65];
    const float* srcs[4] = {w0, w1, w2, w3};
    const float* W  = srcs[blockIdx.z];
    short*       WT = dstbase + (size_t)blockIdx.z * HIDDEN * HIDDEN;
    const int k0 = blockIdx.x * 64, n0 = blockIdx.y * 64;
    const int tid = threadIdx.x;
    #pragma unroll
    for (int it = 0; it < 16; it++) {
        int e = tid + 256 * it;
        int kk = e / 64, nn = e % 64;
        t[kk][nn] = f2bs(W[(size_t)(k0 + kk) * HIDDEN + n0 + nn]);
    }
    __syncthreads();
    #pragma unroll
    for (int it = 0; it < 16; it++) {
        int e = tid + 256 * it;
        int nn = e / 64, kk = e % 64;
        WT[(size_t)(n0 + nn) * HIDDEN + k0 + kk] = t[kk][nn];
    }
}

// ------------------------------------------------------------ V transpose (bf16 -> bf16)
// v [8192][768] -> vT [B*NH][64][1024]   (vT[bh][d][n])
__global__ __launch_bounds__(256) void transpose_v(
    const short* __restrict__ v, short* __restrict__ vT)
{
    __shared__ short t[64][65];
    const int nt = blockIdx.x;           // 16 token tiles
    const int bh = blockIdx.y;           // 96 (b,h)
    const int b = bh / NHEADS, h = bh % NHEADS;
    const int tid = threadIdx.x;
    #pragma unroll
    for (int it = 0; it < 16; it++) {
        int e = tid + 256 * it;
        int rr = e / 64, cc = e % 64;    // cc consecutive -> coalesced
        t[rr][cc] = v[(size_t)(b * NTOK + nt * 64 + rr) * HIDDEN + h * HDIM + cc];
    }
    __syncthreads();
    #pragma unroll
    for (int it = 0; it < 16; it++) {
        int e = tid + 256 * it;
        int c2 = e / 64, r2 = e % 64;    // r2 consecutive -> coalesced
        vT[((size_t)bh * HDIM + c2) * NTOK + nt * 64 + r2] = t[r2][c2];
    }
}

// ------------------------------------------------------------ MFMA GEMM
// A bf16 [M_ALL][K] row-major; WT bf16 [768][K] (= W^T); bias f32 [768].
// MODE 0: out bf16 = acc+bias   (QKV)
// MODE 1: out bf16 = acc+bias+PE(n,d)   (tokens)
// MODE 2: out f32  = acc+bias   (final projection)
template<int MODE>
__global__ __launch_bounds__(256) void gemm_mfma(
    const short* __restrict__ A, const short* __restrict__ WT0, long wt_z,
    const float* __restrict__ b0, const float* __restrict__ b1, const float* __restrict__ b2,
    void* o0, void* o1, void* o2, int K)
{
    __shared__ short Al[128 * 40];   // [row][k] pad 32->40 shorts (80B stride)
    __shared__ short Bl[128 * 40];   // [n][k]
    const int z = blockIdx.z;
    const short* WT  = WT0 + (size_t)z * wt_z;
    const float* bias = (z == 0) ? b0 : (z == 1) ? b1 : b2;
    void* outv        = (z == 0) ? o0 : (z == 1) ? o1 : o2;

    const int tid  = threadIdx.x;
    const int m0   = blockIdx.x * 128;
    const int n0   = blockIdx.y * 128;
    const int lane = tid & 63, wid = tid >> 6;
    const int wm   = (wid >> 1) * 64, wn = (wid & 1) * 64;
    const int l16  = lane & 15, quad = lane >> 4;

    const f32x4 z4 = {0.f, 0.f, 0.f, 0.f};
    f32x4 acc[4][4];
    #pragma unroll
    for (int i = 0; i < 4; i++)
        #pragma unroll
        for (int j = 0; j < 4; j++) acc[i][j] = z4;

    for (int k0 = 0; k0 < K; k0 += 32) {
        #pragma unroll
        for (int it = 0; it < 2; it++) {
            int e = tid + 256 * it;          // 0..511
            int r = e >> 2;                  // 0..127
            int s = e & 3;                   // 8-short segment
            frag8 va = *(const frag8*)&A [(size_t)(m0 + r) * K + k0 + s * 8];
            *(frag8*)&Al[r * 40 + s * 8] = va;
            frag8 vb = *(const frag8*)&WT[(size_t)(n0 + r) * K + k0 + s * 8];
            *(frag8*)&Bl[r * 40 + s * 8] = vb;
        }
        __syncthreads();
        frag8 af[4], bfr[4];
        #pragma unroll
        for (int i = 0; i < 4; i++) af[i]  = *(const frag8*)&Al[(wm + i * 16 + l16) * 40 + quad * 8];
        #pragma unroll
        for (int j = 0; j < 4; j++) bfr[j] = *(const frag8*)&Bl[(wn + j * 16 + l16) * 40 + quad * 8];
        #pragma unroll
        for (int i = 0; i < 4; i++)
            #pragma unroll
            for (int j = 0; j < 4; j++)
                acc[i][j] = __builtin_amdgcn_mfma_f32_16x16x32_bf16(af[i], bfr[j], acc[i][j], 0, 0, 0);
        __syncthreads();
    }

    const float kfac = -9.210340371976184f / 768.0f;  // -ln(10000)/HIDDEN
    #pragma unroll
    for (int i = 0; i < 4; i++) {
        #pragma unroll
        for (int r = 0; r < 4; r++) {
            int m = m0 + wm + i * 16 + quad * 4 + r;   // C/D: row = quad*4+reg
            #pragma unroll
            for (int j = 0; j < 4; j++) {
                int col = n0 + wn + j * 16 + l16;      // C/D: col = lane&15
                float val = acc[i][j][r] + bias[col];
                if (MODE == 1) {
                    int n_tok = m & (NTOK - 1);
                    float ang = (float)n_tok * expf((float)(2 * (col >> 1)) * kfac);
                    val += (col & 1) ? cosf(ang) : sinf(ang);
                }
                if (MODE == 2) ((float*)outv)[(size_t)m * HIDDEN + col] = val;
                else           ((short*)outv)[(size_t)m * HIDDEN + col] = f2bs(val);
            }
        }
    }
}

// ------------------------------------------------------------- MFMA flash attention
// q bf16 [8192][768]; k bf16 [8192][768]; vT bf16 [96][64][1024]; I f32 [8192].
// out bf16 [8192][768] (may alias q: block reads its Q tile before writing same cells).
// grid = 768: 128-row q-tiles, XCD-swizzled so each (b,h)'s 8 blocks share an XCD.
__global__ __launch_bounds__(256, 3) void attn_mfma(
    const short* __restrict__ q, const short* __restrict__ k, const short* __restrict__ vT,
    const float* __restrict__ I, const float* __restrict__ lam_p, short* __restrict__ out)
{
    __shared__ short QP[128 * LSTR];   // Qs first (hoisted to regs), then Ps
    __shared__ short Ks[64 * LSTR];
    __shared__ short Vt[64 * LSTR];
    __shared__ float gL[NTOK];

    const int tid  = threadIdx.x;
    const int lin  = blockIdx.x;
    const int xcd  = lin & 7, slot = lin >> 3;
    const int b    = xcd;                 // group = xcd*12 + slot/8 -> b = group/12 = xcd
    const int h    = slot >> 3;
    const int qt   = slot & 7;
    const float lam = lam_p[0];
    const int lane = tid & 63, wave = tid >> 6;
    const int l16  = lane & 15, quad = lane >> 4;

    // gaussian weights for this batch
    for (int i = tid; i < NTOK; i += 256) gL[i] = gaussw(I[b * NTOK + i]);

    // stage Q tile [128 rows x 64 d]
    #pragma unroll
    for (int it = 0; it < 4; it++) {
        int e = tid + 256 * it;
        int r = e >> 3, seg = e & 7;
        *(frag8*)&QP[r * LSTR + seg * 8] =
            *(const frag8*)&q[(size_t)(b * NTOK + qt * 128 + r) * HIDDEN + h * HDIM + seg * 8];
    }
    __syncthreads();

    // hoist Q A-frags (wave rows = wave*32 + half*16 + l16); Qs LDS then dead -> reused as Ps
    frag8 aq[2][2];
    #pragma unroll
    for (int half = 0; half < 2; half++) {
        aq[half][0] = *(const frag8*)&QP[(wave * 32 + half * 16 + l16) * LSTR + quad * 8];
        aq[half][1] = *(const frag8*)&QP[(wave * 32 + half * 16 + l16) * LSTR + 32 + quad * 8];
    }
    float gi[2][4];
    #pragma unroll
    for (int half = 0; half < 2; half++)
        #pragma unroll
        for (int r = 0; r < 4; r++)
            gi[half][r] = gL[qt * 128 + wave * 32 + half * 16 + quad * 4 + r];

    const f32x4 z4 = {0.f, 0.f, 0.f, 0.f};
    f32x4 o_acc[2][4];
    #pragma unroll
    for (int half = 0; half < 2; half++)
        #pragma unroll
        for (int d = 0; d < 4; d++) o_acc[half][d] = z4;
    float m_run[2][4], l_run[2][4];
    #pragma unroll
    for (int half = 0; half < 2; half++)
        #pragma unroll
        for (int r = 0; r < 4; r++) { m_run[half][r] = -1e30f; l_run[half][r] = 0.f; }

    for (int jt = 0; jt < 16; jt++) {
        __syncthreads();    // prev iteration's Ks/Vt/Ps reads complete
        // stage K tile [64 keys x 64 d] and Vt tile [64 d x 64 keys]
        #pragma unroll
        for (int it = 0; it < 2; it++) {
            int e = tid + 256 * it;
            int r = e >> 3, seg = e & 7;
            *(frag8*)&Ks[r * LSTR + seg * 8] =
                *(const frag8*)&k[(size_t)(b * NTOK + jt * 64 + r) * HIDDEN + h * HDIM + seg * 8];
            *(frag8*)&Vt[r * LSTR + seg * 8] =
                *(const frag8*)&vT[((size_t)(b * NHEADS + h) * HDIM + r) * NTOK + jt * 64 + seg * 8];
        }
        __syncthreads();

        // S = Q.K^T : per wave 32 rows x 64 keys
        float p[2][4][4];
        #pragma unroll
        for (int t4 = 0; t4 < 4; t4++) {
            frag8 bk0 = *(const frag8*)&Ks[(t4 * 16 + l16) * LSTR + quad * 8];
            frag8 bk1 = *(const frag8*)&Ks[(t4 * 16 + l16) * LSTR + 32 + quad * 8];
            #pragma unroll
            for (int half = 0; half < 2; half++) {
                f32x4 a = z4;
                a = __builtin_amdgcn_mfma_f32_16x16x32_bf16(aq[half][0], bk0, a, 0, 0, 0);
                a = __builtin_amdgcn_mfma_f32_16x16x32_bf16(aq[half][1], bk1, a, 0, 0, 0);
                #pragma unroll
                for (int r = 0; r < 4; r++) p[half][t4][r] = a[r];
            }
        }

        // online softmax; row = quad*4+r (owners: 16 lanes sharing quad), col = t4*16+l16
        float gj[4];
        #pragma unroll
        for (int t4 = 0; t4 < 4; t4++) gj[t4] = gL[jt * 64 + t4 * 16 + l16];

        #pragma unroll
        for (int half = 0; half < 2; half++) {
            float mx[4] = {-1e30f, -1e30f, -1e30f, -1e30f};
            #pragma unroll
            for (int t4 = 0; t4 < 4; t4++)
                #pragma unroll
                for (int r = 0; r < 4; r++) {
                    float sv = p[half][t4][r] * 0.125f + lam * gi[half][r] * gj[t4];
                    p[half][t4][r] = sv;
                    mx[r] = fmaxf(mx[r], sv);
                }
            #pragma unroll
            for (int off = 1; off < 16; off <<= 1)
                #pragma unroll
                for (int r = 0; r < 4; r++) mx[r] = fmaxf(mx[r], __shfl_xor(mx[r], off));
            float alpha[4], ls[4];
            #pragma unroll
            for (int r = 0; r < 4; r++) {
                float mn = fmaxf(m_run[half][r], mx[r]);
                alpha[r] = __expf(m_run[half][r] - mn);
                m_run[half][r] = mn;
                ls[r] = 0.f;
            }
            #pragma unroll
            for (int t4 = 0; t4 < 4; t4++)
                #pragma unroll
                for (int r = 0; r < 4; r++) {
                    float e = __expf(p[half][t4][r] - m_run[half][r]);
                    p[half][t4][r] = e;
                    ls[r] += e;
                }
            #pragma unroll
            for (int off = 1; off < 16; off <<= 1)
                #pragma unroll
                for (int r = 0; r < 4; r++) ls[r] += __shfl_xor(ls[r], off);
            #pragma unroll
            for (int r = 0; r < 4; r++) l_run[half][r] = l_run[half][r] * alpha[r] + ls[r];
            // rescale O and write P (wave-private rows -> no barrier needed)
            #pragma unroll
            for (int d = 0; d < 4; d++)
                #pragma unroll
                for (int r = 0; r < 4; r++) o_acc[half][d][r] *= alpha[r];
            #pragma unroll
            for (int t4 = 0; t4 < 4; t4++)
                #pragma unroll
                for (int r = 0; r < 4; r++)
                    QP[(wave * 32 + half * 16 + quad * 4 + r) * LSTR + t4 * 16 + l16]
                        = f2bs(p[half][t4][r]);
        }

        // O += P.V  (Ps rows wave-private; Vt guarded by post-stage barrier)
        frag8 ap[2][2];
        #pragma unroll
        for (int half = 0; half < 2; half++) {
            ap[half][0] = *(const frag8*)&QP[(wave * 32 + half * 16 + l16) * LSTR + quad * 8];
            ap[half][1] = *(const frag8*)&QP[(wave * 32 + half * 16 + l16) * LSTR + 32 + quad * 8];
        }
        #pragma unroll
        for (int d = 0; d < 4; d++) {
            frag8 bv0 = *(const frag8*)&Vt[(d * 16 + l16) * LSTR + quad * 8];
            frag8 bv1 = *(const frag8*)&Vt[(d * 16 + l16) * LSTR + 32 + quad * 8];
            #pragma unroll
            for (int half = 0; half < 2; half++) {
                o_acc[half][d] = __builtin_amdgcn_mfma_f32_16x16x32_bf16(ap[half][0], bv0, o_acc[half][d], 0, 0, 0);
                o_acc[half][d] = __builtin_amdgcn_mfma_f32_16x16x32_bf16(ap[half][1], bv1, o_acc[half][d], 0, 0, 0);
            }
        }
    }

    // epilogue
    #pragma unroll
    for (int half = 0; half < 2; half++)
        #pragma unroll
        for (int r = 0; r < 4; r++) {
            float inv_l = 1.0f / l_run[half][r];
            int row = qt * 128 + wave * 32 + half * 16 + quad * 4 + r;
            #pragma unroll
            for (int d = 0; d < 4; d++)
                out[(size_t)(b * NTOK + row) * HIDDEN + h * HDIM + d * 16 + l16]
                    = f2bs(o_acc[half][d][r] * inv_l);
        }
}

// ---------------------------------------------------------------- launch
extern "C" void kernel_launch(void* const* d_in, const int* in_sizes, int n_in,
                              void* d_out, int out_size, void* d_ws, size_t ws_size,
                              hipStream_t stream)
{
    const float* feat   = (const float*)d_in[0];
    const float* I      = (const float*)d_in[1];
    const float* proj_w = (const float*)d_in[2];
    const float* proj_b = (const float*)d_in[3];
    const float* wq     = (const float*)d_in[4];
    const float* bq     = (const float*)d_in[5];
    const float* wk     = (const float*)d_in[6];
    const float* bk     = (const float*)d_in[7];
    const float* wv     = (const float*)d_in[8];
    const float* bv     = (const float*)d_in[9];
    const float* wo     = (const float*)d_in[10];
    const float* bo     = (const float*)d_in[11];
    const float* lam    = (const float*)d_in[12];
    float* out = (float*)d_out;

    // ws layout (shorts), ~30.3 MB total (same as round 6):
    short* wtqkv = (short*)d_ws;                          // 3 x 768x768 (+wo contiguous after)
    short* wto   = wtqkv + (size_t)3 * HIDDEN * HIDDEN;
    short* wtp   = wto   + (size_t)HIDDEN * HIDDEN;
    short* tokens= wtp   + (size_t)HIDDEN * CIN;          // 12.58 MB; later reused for vT
    short* qbuf  = tokens+ (size_t)M_ALL * HIDDEN;        // featT first, q later, attn-out in place
    short* featT = qbuf;                                  // [B][1024][256] = 4.19MB
    short* vTb   = tokens;                                // vT [96][64][1024], tokens dead after QKV
    short* kbuf  = (short*)d_out;                         // k,v in d_out (dead before final write)
    short* vbuf  = kbuf + (size_t)M_ALL * HIDDEN;

    // 1. fused weight transposes (wq,wk,wv -> wtqkv planes; wo -> wto, contiguous plane 3)
    transpose_w4<<<dim3(12, 12, 4), 256, 0, stream>>>(wq, wk, wv, wo, wtqkv);
    transpose_cvt<<<dim3(4, 12, 1), 256, 0, stream>>>(proj_w, wtp, 256, 768, 0, 0);
    // 2. feat [B][C][N] -> featT [B][N][C] bf16
    transpose_cvt<<<dim3(4, 16, 8), 256, 0, stream>>>(feat, featT, 256, 1024,
                                                      (long)CIN * NTOK, (long)NTOK * CIN);
    // 3. tokens = featT @ proj_w + b + PE
    gemm_mfma<1><<<dim3(64, 6, 1), 256, 0, stream>>>(featT, wtp, 0,
                                                     proj_b, proj_b, proj_b,
                                                     tokens, tokens, tokens, CIN);
    // 4. fused QKV
    gemm_mfma<0><<<dim3(64, 6, 3), 256, 0, stream>>>(tokens, wtqkv, (long)HIDDEN * HIDDEN,
                                                     bq, bk, bv,
                                                     qbuf, kbuf, vbuf, HIDDEN);
    // 5. V transpose: vbuf [8192][768] -> vT [96][64][1024] (tokens region, now dead)
    transpose_v<<<dim3(16, 96), 256, 0, stream>>>(vbuf, vTb);
    // 6. attention (MFMA flash, 128-row q-tiles, out in-place into qbuf)
    attn_mfma<<<768, 256, 0, stream>>>(qbuf, kbuf, vTb, I, lam, qbuf);
    // 7. final projection (f32 out, overwrites kbuf/vbuf in d_out)
    gemm_mfma<2><<<dim3(64, 6, 1), 256, 0, stream>>>(qbuf, wto, 0,
                                                     bo, bo, bo,
                                                     out, out, out, HIDDEN);
}

// Round 8
// 319.915 us; speedup vs baseline: 17.4987x; 1.0304x over previous
//
#include <hip/hip_runtime.h>
#include <hip/hip_bf16.h>
#include <math.h>

#define HIDDEN 768
#define NHEADS 12
#define HDIM   64
#define NTOK   1024   // 32*32
#define BATCH  8
#define CIN    256
#define M_ALL  (BATCH * NTOK)   // 8192
#define LSTR   72               // padded stride for QP (register-sourced writes)

typedef __hip_bfloat16 bf16;
typedef short frag8 __attribute__((ext_vector_type(8)));   // 8 bf16 = 4 VGPRs
typedef float f32x4 __attribute__((ext_vector_type(4)));

#define GL2LDS(gp, lp) \
    __builtin_amdgcn_global_load_lds((const __attribute__((address_space(1))) void*)(gp), \
                                     (__attribute__((address_space(3))) void*)(lp), 16, 0, 0)

__device__ __forceinline__ short f2bs(float x){
    union { bf16 h; short s; } u; u.h = __float2bfloat16(x); return u.s;
}

// Gaussian weight (inference buffers mu=0 sigma=1)
__device__ __forceinline__ float gaussw(float x){
    float x2 = x * x;
    return (__expf(-x2 / 0.50001f) + __expf(-x2 / 2.00001f) + __expf(-x2 / 8.00001f)) * (1.0f / 3.0f);
}

// ------------------------------------------------------------ transpose+cvt (generic, f32 -> bf16)
__global__ __launch_bounds__(256) void transpose_cvt(
    const float* __restrict__ in, short* __restrict__ out,
    int K, int N, long in_z, long out_z)
{
    __shared__ short t[64][65];
    const float* W  = in  + (size_t)blockIdx.z * in_z;
    short*       WT = out + (size_t)blockIdx.z * out_z;
    const int k0 = blockIdx.x * 64, n0 = blockIdx.y * 64;
    const int tid = threadIdx.x;
    #pragma unroll
    for (int it = 0; it < 16; it++) {
        int e = tid + 256 * it;
        int kk = e / 64, nn = e % 64;
        t[kk][nn] = f2bs(W[(size_t)(k0 + kk) * N + n0 + nn]);
    }
    __syncthreads();
    #pragma unroll
    for (int it = 0; it < 16; it++) {
        int e = tid + 256 * it;
        int nn = e / 64, kk = e % 64;
        WT[(size_t)(n0 + nn) * K + k0 + kk] = t[kk][nn];
    }
}

// ------------------------------------------------------------ fused 4x 768x768 weight transpose
__global__ __launch_bounds__(256) void transpose_w4(
    const float* __restrict__ w0, const float* __restrict__ w1,
    const float* __restrict__ w2, const float* __restrict__ w3,
    short* __restrict__ dstbase)
{
    __shared__ short t[64][65];
    const float* srcs[4] = {w0, w1, w2, w3};
    const float* W  = srcs[blockIdx.z];
    short*       WT = dstbase + (size_t)blockIdx.z * HIDDEN * HIDDEN;
    const int k0 = blockIdx.x * 64, n0 = blockIdx.y * 64;
    const int tid = threadIdx.x;
    #pragma unroll
    for (int it = 0; it < 16; it++) {
        int e = tid + 256 * it;
        int kk = e / 64, nn = e % 64;
        t[kk][nn] = f2bs(W[(size_t)(k0 + kk) * HIDDEN + n0 + nn]);
    }
    __syncthreads();
    #pragma unroll
    for (int it = 0; it < 16; it++) {
        int e = tid + 256 * it;
        int nn = e / 64, kk = e % 64;
        WT[(size_t)(n0 + nn) * HIDDEN + k0 + kk] = t[kk][nn];
    }
}

// ------------------------------------------------------------ V transpose (bf16 -> bf16)
// v [8192][768] -> vT [B*NH][64][1024]   (vT[bh][d][n])
__global__ __launch_bounds__(256) void transpose_v(
    const short* __restrict__ v, short* __restrict__ vT)
{
    __shared__ short t[64][65];
    const int nt = blockIdx.x;
    const int bh = blockIdx.y;
    const int b = bh / NHEADS, h = bh % NHEADS;
    const int tid = threadIdx.x;
    #pragma unroll
    for (int it = 0; it < 16; it++) {
        int e = tid + 256 * it;
        int rr = e / 64, cc = e % 64;
        t[rr][cc] = v[(size_t)(b * NTOK + nt * 64 + rr) * HIDDEN + h * HDIM + cc];
    }
    __syncthreads();
    #pragma unroll
    for (int it = 0; it < 16; it++) {
        int e = tid + 256 * it;
        int c2 = e / 64, r2 = e % 64;
        vT[((size_t)bh * HDIM + c2) * NTOK + nt * 64 + r2] = t[r2][c2];
    }
}

// ------------------------------------------------------------ MFMA GEMM (global_load_lds staging)
// A bf16 [M_ALL][K]; WT bf16 [768][K]; bias f32 [768].
// LDS tiles unpadded [128][32] shorts, XOR-swizzled: LDS[r][s] = G[r][s ^ ((r>>1)&3)] (16B segs)
template<int MODE>
__global__ __launch_bounds__(256) void gemm_mfma(
    const short* __restrict__ A, const short* __restrict__ WT0, long wt_z,
    const float* __restrict__ b0, const float* __restrict__ b1, const float* __restrict__ b2,
    void* o0, void* o1, void* o2, int K)
{
    __shared__ short Al[128 * 32];
    __shared__ short Bl[128 * 32];
    const int z = blockIdx.z;
    const short* WT  = WT0 + (size_t)z * wt_z;
    const float* bias = (z == 0) ? b0 : (z == 1) ? b1 : b2;
    void* outv        = (z == 0) ? o0 : (z == 1) ? o1 : o2;

    const int tid  = threadIdx.x;
    const int m0   = blockIdx.x * 128;
    const int n0   = blockIdx.y * 128;
    const int lane = tid & 63, wid = tid >> 6;
    const int wm   = (wid >> 1) * 64, wn = (wid & 1) * 64;
    const int l16  = lane & 15, quad = lane >> 4;

    // staging lane mapping (16B granules): row r_l = lane>>2, seg = lane&3, swizzled source seg
    const int sr  = lane >> 2;            // row within 16-row group
    const int ssg = (lane & 3) ^ ((sr >> 1) & 3);
    // frag-read swizzle: f = (l16>>1)&3 (rows of a frag group are base(l16-aligned)+l16)
    const int fsw = (l16 >> 1) & 3;

    const f32x4 z4 = {0.f, 0.f, 0.f, 0.f};
    f32x4 acc[4][4];
    #pragma unroll
    for (int i = 0; i < 4; i++)
        #pragma unroll
        for (int j = 0; j < 4; j++) acc[i][j] = z4;

    for (int k0 = 0; k0 < K; k0 += 32) {
        #pragma unroll
        for (int t = 0; t < 2; t++) {
            int rbase = wid * 32 + t * 16;
            int r = rbase + sr;
            GL2LDS(A  + (size_t)(m0 + r) * K + k0 + ssg * 8, &Al[rbase * 32]);
            GL2LDS(WT + (size_t)(n0 + r) * K + k0 + ssg * 8, &Bl[rbase * 32]);
        }
        __syncthreads();
        frag8 af[4], bfr[4];
        #pragma unroll
        for (int i = 0; i < 4; i++)
            af[i]  = *(const frag8*)&Al[(wm + i * 16 + l16) * 32 + ((quad ^ fsw) * 8)];
        #pragma unroll
        for (int j = 0; j < 4; j++)
            bfr[j] = *(const frag8*)&Bl[(wn + j * 16 + l16) * 32 + ((quad ^ fsw) * 8)];
        #pragma unroll
        for (int i = 0; i < 4; i++)
            #pragma unroll
            for (int j = 0; j < 4; j++)
                acc[i][j] = __builtin_amdgcn_mfma_f32_16x16x32_bf16(af[i], bfr[j], acc[i][j], 0, 0, 0);
        __syncthreads();
    }

    const float kfac = -9.210340371976184f / 768.0f;  // -ln(10000)/HIDDEN
    #pragma unroll
    for (int i = 0; i < 4; i++) {
        #pragma unroll
        for (int r = 0; r < 4; r++) {
            int m = m0 + wm + i * 16 + quad * 4 + r;
            #pragma unroll
            for (int j = 0; j < 4; j++) {
                int col = n0 + wn + j * 16 + l16;
                float val = acc[i][j][r] + bias[col];
                if (MODE == 1) {
                    int n_tok = m & (NTOK - 1);
                    float ang = (float)n_tok * expf((float)(2 * (col >> 1)) * kfac);
                    val += (col & 1) ? cosf(ang) : sinf(ang);
                }
                if (MODE == 2) ((float*)outv)[(size_t)m * HIDDEN + col] = val;
                else           ((short*)outv)[(size_t)m * HIDDEN + col] = f2bs(val);
            }
        }
    }
}

// ------------------------------------------------------------- MFMA flash attention
// q bf16 [8192][768]; k bf16 [8192][768]; vT bf16 [96][64][1024]; I f32 [8192].
// out may alias q. grid = 768, XCD-swizzled. Ks/Vt: unpadded [64][64] shorts,
// global_load_lds staged, swizzle LDS[r][s] = G[r][s ^ (r&7)] (16B segs, 8 segs/row).
__global__ __launch_bounds__(256, 3) void attn_mfma(
    const short* __restrict__ q, const short* __restrict__ k, const short* __restrict__ vT,
    const float* __restrict__ I, const float* __restrict__ lam_p, short* __restrict__ out)
{
    __shared__ short QP[128 * LSTR];   // Q staging (then P), padded — register-sourced writes
    __shared__ short Ks[64 * 64];
    __shared__ short Vt[64 * 64];
    __shared__ float gL[NTOK];

    const int tid  = threadIdx.x;
    const int lin  = blockIdx.x;
    const int xcd  = lin & 7, slot = lin >> 3;
    const int b    = xcd;
    const int h    = slot >> 3;
    const int qt   = slot & 7;
    const float lam = lam_p[0];
    const int lane = tid & 63, wave = tid >> 6;
    const int l16  = lane & 15, quad = lane >> 4;

    // staging lane mapping for 128B rows: row = lane>>3, seg = lane&7, swizzled seg
    const int sr  = lane >> 3;
    const int ssg = (lane & 7) ^ (sr & 7);
    // frag-read swizzle: rows base+l16, base mult of 16 -> f = l16&7
    const int fsw = l16 & 7;

    for (int i = tid; i < NTOK; i += 256) gL[i] = gaussw(I[b * NTOK + i]);

    // stage Q tile [128 x 64] (normal loads, padded QP)
    #pragma unroll
    for (int it = 0; it < 4; it++) {
        int e = tid + 256 * it;
        int r = e >> 3, seg = e & 7;
        *(frag8*)&QP[r * LSTR + seg * 8] =
            *(const frag8*)&q[(size_t)(b * NTOK + qt * 128 + r) * HIDDEN + h * HDIM + seg * 8];
    }
    __syncthreads();

    frag8 aq[2][2];
    #pragma unroll
    for (int half = 0; half < 2; half++) {
        aq[half][0] = *(const frag8*)&QP[(wave * 32 + half * 16 + l16) * LSTR + quad * 8];
        aq[half][1] = *(const frag8*)&QP[(wave * 32 + half * 16 + l16) * LSTR + 32 + quad * 8];
    }
    float gi[2][4];
    #pragma unroll
    for (int half = 0; half < 2; half++)
        #pragma unroll
        for (int r = 0; r < 4; r++)
            gi[half][r] = gL[qt * 128 + wave * 32 + half * 16 + quad * 4 + r];

    const f32x4 z4 = {0.f, 0.f, 0.f, 0.f};
    f32x4 o_acc[2][4];
    #pragma unroll
    for (int half = 0; half < 2; half++)
        #pragma unroll
        for (int d = 0; d < 4; d++) o_acc[half][d] = z4;
    float m_run[2][4], l_run[2][4];
    #pragma unroll
    for (int half = 0; half < 2; half++)
        #pragma unroll
        for (int r = 0; r < 4; r++) { m_run[half][r] = -1e30f; l_run[half][r] = 0.f; }

    const size_t kb  = (size_t)b * NTOK * HIDDEN + h * HDIM;
    const size_t vtb = (size_t)(b * NHEADS + h) * HDIM * NTOK;

    for (int jt = 0; jt < 16; jt++) {
        __syncthreads();
        // async stage K tile [64 keys x 64 d] and Vt tile [64 d x 64 keys]
        #pragma unroll
        for (int t = 0; t < 2; t++) {
            int rbase = wave * 16 + t * 8;
            int r = rbase + sr;
            GL2LDS(k  + kb  + (size_t)(jt * 64 + r) * HIDDEN + ssg * 8, &Ks[rbase * 64]);
            GL2LDS(vT + vtb + (size_t)r * NTOK + jt * 64 + ssg * 8,     &Vt[rbase * 64]);
        }
        __syncthreads();

        // S = Q.K^T
        float p[2][4][4];
        #pragma unroll
        for (int t4 = 0; t4 < 4; t4++) {
            frag8 bk0 = *(const frag8*)&Ks[(t4 * 16 + l16) * 64 + ((quad ^ fsw) * 8)];
            frag8 bk1 = *(const frag8*)&Ks[(t4 * 16 + l16) * 64 + (((quad + 4) ^ fsw) * 8)];
            #pragma unroll
            for (int half = 0; half < 2; half++) {
                f32x4 a = z4;
                a = __builtin_amdgcn_mfma_f32_16x16x32_bf16(aq[half][0], bk0, a, 0, 0, 0);
                a = __builtin_amdgcn_mfma_f32_16x16x32_bf16(aq[half][1], bk1, a, 0, 0, 0);
                #pragma unroll
                for (int r = 0; r < 4; r++) p[half][t4][r] = a[r];
            }
        }

        float gj[4];
        #pragma unroll
        for (int t4 = 0; t4 < 4; t4++) gj[t4] = gL[jt * 64 + t4 * 16 + l16];

        #pragma unroll
        for (int half = 0; half < 2; half++) {
            float mx[4] = {-1e30f, -1e30f, -1e30f, -1e30f};
            #pragma unroll
            for (int t4 = 0; t4 < 4; t4++)
                #pragma unroll
                for (int r = 0; r < 4; r++) {
                    float sv = p[half][t4][r] * 0.125f + lam * gi[half][r] * gj[t4];
                    p[half][t4][r] = sv;
                    mx[r] = fmaxf(mx[r], sv);
                }
            #pragma unroll
            for (int off = 1; off < 16; off <<= 1)
                #pragma unroll
                for (int r = 0; r < 4; r++) mx[r] = fmaxf(mx[r], __shfl_xor(mx[r], off));
            float alpha[4], ls[4];
            #pragma unroll
            for (int r = 0; r < 4; r++) {
                float mn = fmaxf(m_run[half][r], mx[r]);
                alpha[r] = __expf(m_run[half][r] - mn);
                m_run[half][r] = mn;
                ls[r] = 0.f;
            }
            #pragma unroll
            for (int t4 = 0; t4 < 4; t4++)
                #pragma unroll
                for (int r = 0; r < 4; r++) {
                    float e = __expf(p[half][t4][r] - m_run[half][r]);
                    p[half][t4][r] = e;
                    ls[r] += e;
                }
            #pragma unroll
            for (int off = 1; off < 16; off <<= 1)
                #pragma unroll
                for (int r = 0; r < 4; r++) ls[r] += __shfl_xor(ls[r], off);
            #pragma unroll
            for (int r = 0; r < 4; r++) l_run[half][r] = l_run[half][r] * alpha[r] + ls[r];
            #pragma unroll
            for (int d = 0; d < 4; d++)
                #pragma unroll
                for (int r = 0; r < 4; r++) o_acc[half][d][r] *= alpha[r];
            #pragma unroll
            for (int t4 = 0; t4 < 4; t4++)
                #pragma unroll
                for (int r = 0; r < 4; r++)
                    QP[(wave * 32 + half * 16 + quad * 4 + r) * LSTR + t4 * 16 + l16]
                        = f2bs(p[half][t4][r]);
        }

        // O += P.V
        frag8 ap[2][2];
        #pragma unroll
        for (int half = 0; half < 2; half++) {
            ap[half][0] = *(const frag8*)&QP[(wave * 32 + half * 16 + l16) * LSTR + quad * 8];
            ap[half][1] = *(const frag8*)&QP[(wave * 32 + half * 16 + l16) * LSTR + 32 + quad * 8];
        }
        #pragma unroll
        for (int d = 0; d < 4; d++) {
            frag8 bv0 = *(const frag8*)&Vt[(d * 16 + l16) * 64 + ((quad ^ fsw) * 8)];
            frag8 bv1 = *(const frag8*)&Vt[(d * 16 + l16) * 64 + (((quad + 4) ^ fsw) * 8)];
            #pragma unroll
            for (int half = 0; half < 2; half++) {
                o_acc[half][d] = __builtin_amdgcn_mfma_f32_16x16x32_bf16(ap[half][0], bv0, o_acc[half][d], 0, 0, 0);
                o_acc[half][d] = __builtin_amdgcn_mfma_f32_16x16x32_bf16(ap[half][1], bv1, o_acc[half][d], 0, 0, 0);
            }
        }
    }

    #pragma unroll
    for (int half = 0; half < 2; half++)
        #pragma unroll
        for (int r = 0; r < 4; r++) {
            float inv_l = 1.0f / l_run[half][r];
            int row = qt * 128 + wave * 32 + half * 16 + quad * 4 + r;
            #pragma unroll
            for (int d = 0; d < 4; d++)
                out[(size_t)(b * NTOK + row) * HIDDEN + h * HDIM + d * 16 + l16]
                    = f2bs(o_acc[half][d][r] * inv_l);
        }
}

// ---------------------------------------------------------------- launch
extern "C" void kernel_launch(void* const* d_in, const int* in_sizes, int n_in,
                              void* d_out, int out_size, void* d_ws, size_t ws_size,
                              hipStream_t stream)
{
    const float* feat   = (const float*)d_in[0];
    const float* I      = (const float*)d_in[1];
    const float* proj_w = (const float*)d_in[2];
    const float* proj_b = (const float*)d_in[3];
    const float* wq     = (const float*)d_in[4];
    const float* bq     = (const float*)d_in[5];
    const float* wk     = (const float*)d_in[6];
    const float* bk     = (const float*)d_in[7];
    const float* wv     = (const float*)d_in[8];
    const float* bv     = (const float*)d_in[9];
    const float* wo     = (const float*)d_in[10];
    const float* bo     = (const float*)d_in[11];
    const float* lam    = (const float*)d_in[12];
    float* out = (float*)d_out;

    short* wtqkv = (short*)d_ws;
    short* wto   = wtqkv + (size_t)3 * HIDDEN * HIDDEN;
    short* wtp   = wto   + (size_t)HIDDEN * HIDDEN;
    short* tokens= wtp   + (size_t)HIDDEN * CIN;
    short* qbuf  = tokens+ (size_t)M_ALL * HIDDEN;
    short* featT = qbuf;
    short* vTb   = tokens;
    short* kbuf  = (short*)d_out;
    short* vbuf  = kbuf + (size_t)M_ALL * HIDDEN;

    transpose_w4<<<dim3(12, 12, 4), 256, 0, stream>>>(wq, wk, wv, wo, wtqkv);
    transpose_cvt<<<dim3(4, 12, 1), 256, 0, stream>>>(proj_w, wtp, 256, 768, 0, 0);
    transpose_cvt<<<dim3(4, 16, 8), 256, 0, stream>>>(feat, featT, 256, 1024,
                                                      (long)CIN * NTOK, (long)NTOK * CIN);
    gemm_mfma<1><<<dim3(64, 6, 1), 256, 0, stream>>>(featT, wtp, 0,
                                                     proj_b, proj_b, proj_b,
                                                     tokens, tokens, tokens, CIN);
    gemm_mfma<0><<<dim3(64, 6, 3), 256, 0, stream>>>(tokens, wtqkv, (long)HIDDEN * HIDDEN,
                                                     bq, bk, bv,
                                                     qbuf, kbuf, vbuf, HIDDEN);
    transpose_v<<<dim3(16, 96), 256, 0, stream>>>(vbuf, vTb);
    attn_mfma<<<768, 256, 0, stream>>>(qbuf, kbuf, vTb, I, lam, qbuf);
    gemm_mfma<2><<<dim3(64, 6, 1), 256, 0, stream>>>(qbuf, wto, 0,
                                                     bo, bo, bo,
                                                     out, out, out, HIDDEN);
}